// Round 9
// baseline (269.610 us; speedup 1.0000x reference)
//
#include <hip/hip_runtime.h>
#include <hip/hip_bf16.h>

#define NN   50000
#define EE   1600000
#define FIN  128
#define FOUT 64
#define BETA  0.5f
#define ALPHA 0.2f
#define BW     64           // src rows per bucket
#define NB     782          // ceil(NN/BW)
#define PGRID  128          // partition blocks
#define PCHUNK 12500        // EE/PGRID exact; avg run/bucket = 16 recs = 128 B
#define HGRID  400          // bucket-hist blocks
#define HCHUNK 4000         // EE/HGRID exact
#define CAP    4096         // bucket_csr LDS record cache (recs); fallback if exceeded
#define XS     152          // LDS stride (bf16 elems): 304 B = 19x16 aligned, 2-way-free banks

typedef __attribute__((ext_vector_type(8))) short short8;
typedef __attribute__((ext_vector_type(4))) float float4v;

// Read element i of a buffer that is either fp32 (isf32=1) or bf16 (isf32=0).
__device__ __forceinline__ float load_any(const void* p, long i, int isf32) {
    if (isf32) return ((const float*)p)[i];
    unsigned int b = ((unsigned int)(((const unsigned short*)p)[i])) << 16;
    return __uint_as_float(b);
}

__device__ __forceinline__ unsigned short f32_to_bf16_rne(float f) {
    unsigned int b = __float_as_uint(f);
    return (unsigned short)((b + 0x7FFF + ((b >> 16) & 1)) >> 16);
}

__device__ __forceinline__ float bf16_to_f32(unsigned short u) {
    return __uint_as_float(((unsigned int)u) << 16);
}

// ---------------------------------------------------------------------------
// Kernel 0: sampled dtype detection. flags[t]=1 means fp32.
// ---------------------------------------------------------------------------
__global__ __launch_bounds__(256) void detect_kernel(
    const void* inp, const void* Mv, const void* W, const void* a, int* flags)
{
    const void* ptrs[4] = { inp, Mv, W, a };
    const long  cnts[4] = { (long)NN * FIN, (long)EE, (long)FIN * FOUT, 2L * FOUT };
    const int t = blockIdx.x;
    const unsigned short* p = (const unsigned short*)ptrs[t];
    const long half = cnts[t] >> 1;
    long step = half / 256; if (step == 0) step = 1;
    const long pos = 2 * (((long)threadIdx.x * step) % half);

    const float v = bf16_to_f32(p[pos]);
    const int bad = (isnan(v) || fabsf(v) > 1e4f) ? 1 : 0;

    __shared__ int sbad[256];
    sbad[threadIdx.x] = bad;
    __syncthreads();
    for (int s = 128; s > 0; s >>= 1) {
        if (threadIdx.x < (unsigned)s) sbad[threadIdx.x] |= sbad[threadIdx.x + s];
        __syncthreads();
    }
    if (threadIdx.x == 0) flags[t] = sbad[0];
}

// ---------------------------------------------------------------------------
// Kernel 1: MFMA gemm. 16 rows/block (3125 blocks exact); stage X-tile and
// W^T in LDS as bf16; each wave computes one 16x16 tile via 4x
// mfma_f32_16x16x32_bf16 over K=128. Fused s1/s2: 16-lane butterfly + LDS
// cross-wave reduce. C layout: col=lane&15, row=quad*4+reg (m89-verified).
// A layout: A[m=lane&15][k=quad*8+j]; B mirrors with n=lane&15.
// ---------------------------------------------------------------------------
__global__ __launch_bounds__(256) void mfma_gemm_kernel(
    const void* __restrict__ inp,
    const void* __restrict__ W,
    const void* __restrict__ a,
    const int* __restrict__ flags,
    unsigned short* __restrict__ h,
    float* __restrict__ s1,
    float* __restrict__ s2)
{
    __shared__ unsigned short Xs[16 * XS];   // 4.75 KB
    __shared__ unsigned short Wt[64 * XS];   // 19 KB, Wt[n][k]
    __shared__ float part1[4][16];
    __shared__ float part2[4][16];

    const int tid  = threadIdx.x;
    const int wave = tid >> 6;
    const int lane = tid & 63;
    const int quad = lane >> 4;
    const int col  = lane & 15;
    const int rb   = blockIdx.x * 16;

    const int fI = flags[0], fW = flags[2], fA = flags[3];

    // stage X rows (16x128) as bf16 (bf16->f32->bf16 RNE is identity)
    for (int i = tid; i < 16 * FIN; i += 256) {
        const int r = i >> 7, k = i & 127;
        Xs[r * XS + k] = f32_to_bf16_rne(load_any(inp, (long)(rb + r) * FIN + k, fI));
    }
    // stage W transposed: Wt[n][k] (consecutive tids -> consecutive k)
    for (int i = tid; i < FIN * FOUT; i += 256) {
        const int k = i & 127, n = i >> 7;
        Wt[n * XS + k] = f32_to_bf16_rne(load_any(W, (long)k * FOUT + n, fW));
    }
    __syncthreads();

    const int nb = wave * 16;   // this wave's column base
    float4v acc = { 0.f, 0.f, 0.f, 0.f };
    #pragma unroll
    for (int k0 = 0; k0 < FIN; k0 += 32) {
        const short8 af = *(const short8*)&Xs[col * XS + k0 + quad * 8];
        const short8 bf = *(const short8*)&Wt[(nb + col) * XS + k0 + quad * 8];
        acc = __builtin_amdgcn_mfma_f32_16x16x32_bf16(af, bf, acc, 0, 0, 0);
    }

    // write h (bf16)
    #pragma unroll
    for (int r = 0; r < 4; ++r)
        h[(long)(rb + quad * 4 + r) * FOUT + nb + col] = f32_to_bf16_rne(acc[r]);

    // fused projections: per-row sums of acc*a over this wave's 16 cols
    const float a1 = load_any(a, nb + col, fA);
    const float a2 = load_any(a, 64 + nb + col, fA);
    #pragma unroll
    for (int r = 0; r < 4; ++r) {
        float v1 = acc[r] * a1;
        float v2 = acc[r] * a2;
        #pragma unroll
        for (int o = 1; o < 16; o <<= 1) {
            v1 += __shfl_xor(v1, o, 64);
            v2 += __shfl_xor(v2, o, 64);
        }
        if (col == 0) {
            part1[wave][quad * 4 + r] = v1;
            part2[wave][quad * 4 + r] = v2;
        }
    }
    __syncthreads();
    if (tid < 16) {
        s1[rb + tid] = part1[0][tid] + part1[1][tid] + part1[2][tid] + part1[3][tid];
        s2[rb + tid] = part2[0][tid] + part2[1][tid] + part2[2][tid] + part2[3][tid];
    }
}

// ---------------------------------------------------------------------------
// Kernel 2: bucket histogram (bucket = src >> 6), LDS-staged.
// ---------------------------------------------------------------------------
__global__ __launch_bounds__(256) void bucket_hist_kernel(
    const int* __restrict__ edge, int* __restrict__ bcnt)
{
    __shared__ int cnt[NB];
    for (int i = threadIdx.x; i < NB; i += 256) cnt[i] = 0;
    __syncthreads();
    const int e0 = blockIdx.x * HCHUNK;
    for (int e = e0 + threadIdx.x; e < e0 + HCHUNK; e += 256)
        atomicAdd(&cnt[edge[e] >> 6], 1);
    __syncthreads();
    for (int i = threadIdx.x; i < NB; i += 256)
        if (cnt[i]) atomicAdd(&bcnt[i], cnt[i]);
}

// ---------------------------------------------------------------------------
// Kernel 3: exclusive scan of bcnt[NB] -> base[NB+1]; bcur = base.
// ---------------------------------------------------------------------------
__global__ __launch_bounds__(1024) void bucket_scan_kernel(
    const int* __restrict__ bcnt, int* __restrict__ base, int* __restrict__ bcur)
{
    const int tid = threadIdx.x, wave = tid >> 6, lane = tid & 63;
    const int c = (tid < NB) ? bcnt[tid] : 0;
    int x = c;
    #pragma unroll
    for (int off = 1; off < 64; off <<= 1) {
        int y = __shfl_up(x, off, 64);
        if (lane >= off) x += y;
    }
    __shared__ int wsum[16];
    if (lane == 63) wsum[wave] = x;
    __syncthreads();
    int wb = 0;
    for (int w = 0; w < wave; ++w) wb += wsum[w];
    if (tid < NB) {
        const int v = wb + x - c;
        base[tid] = v;
        bcur[tid] = v;
    }
    if (tid == 0) base[NB] = EE;
}

// ---------------------------------------------------------------------------
// Kernel 4: partition. Per block: LDS-count its chunk per bucket, reserve ONE
// contiguous run per bucket (single global atomic on bcur), append u64 recs.
// PCHUNK=12500 -> avg run 16 recs = 128 B -> ~2 sectors/run, low write amp.
// Record: src<<32 | dst<<16 | bf16(edge_e).
// ---------------------------------------------------------------------------
__global__ __launch_bounds__(256) void partition_kernel(
    const int* __restrict__ edge,
    const void* __restrict__ Mv,
    const int* __restrict__ flags,
    const float* __restrict__ s1,
    const float* __restrict__ s2,
    int* __restrict__ bcur,
    unsigned long long* __restrict__ recs)
{
    __shared__ int lcnt[NB];
    __shared__ int lbase[NB];
    const int tid = threadIdx.x;
    const int fM = flags[1];
    const int e0 = blockIdx.x * PCHUNK;

    for (int i = tid; i < NB; i += 256) lcnt[i] = 0;
    __syncthreads();

    for (int e = e0 + tid; e < e0 + PCHUNK; e += 256)
        atomicAdd(&lcnt[edge[e] >> 6], 1);
    __syncthreads();

    for (int i = tid; i < NB; i += 256) {
        const int c = lcnt[i];
        lbase[i] = c ? atomicAdd(&bcur[i], c) : 0;
        lcnt[i] = 0;                 // reuse as rank counter
    }
    __syncthreads();

    for (int e = e0 + tid; e < e0 + PCHUNK; e += 256) {
        const int src = edge[e];
        const int dst = edge[EE + e];
        const float bias = load_any(Mv, e, fM) * BETA + (1.f - BETA);
        const float x  = s1[src] + bias * s2[dst];
        const float lr = x > 0.f ? x : ALPHA * x;
        const float ee = __expf(lr);
        const int b = src >> 6;
        const int r = atomicAdd(&lcnt[b], 1);
        recs[lbase[b] + r] = ((unsigned long long)(unsigned)src << 32)
                           | ((unsigned long long)(unsigned)dst << 16)
                           | (unsigned long long)f32_to_bf16_rne(ee);
    }
}

// ---------------------------------------------------------------------------
// Kernel 5: within-bucket CSR finalize + rowptr derivation.
// ---------------------------------------------------------------------------
__global__ __launch_bounds__(256) void bucket_csr_kernel(
    const int* __restrict__ base,
    const unsigned long long* __restrict__ recs,
    unsigned int* __restrict__ pairs,
    int* __restrict__ rowptr)
{
    __shared__ unsigned long long lrec[CAP];   // 32 KB
    __shared__ int cnt[BW];
    __shared__ int off[BW];
    const int b   = blockIdx.x;
    const int tid = threadIdx.x;
    const int rb  = b * BW;

    const int beg = base[b];
    const int end = base[b + 1];
    const int n   = end - beg;
    const bool fits = (n <= CAP);

    if (tid < BW) cnt[tid] = 0;
    __syncthreads();

    for (int j = tid; j < n; j += 256) {
        const unsigned long long rec = recs[beg + j];
        if (fits) lrec[j] = rec;
        atomicAdd(&cnt[(int)(rec >> 32) - rb], 1);
    }
    __syncthreads();

    if (tid < BW) {   // single wave: exclusive scan of 64 counters
        const int c = cnt[tid];
        int x = c;
        #pragma unroll
        for (int o = 1; o < 64; o <<= 1) {
            int y = __shfl_up(x, o, 64);
            if ((tid & 63) >= o) x += y;
        }
        off[tid] = x - c;
        const int row = rb + tid;
        if (row < NN) rowptr[row] = beg + x - c;
        cnt[tid] = 0;  // reuse as rank counters
    }
    if (b == NB - 1 && tid == 0) rowptr[NN] = EE;
    __syncthreads();

    for (int j = tid; j < n; j += 256) {
        const unsigned long long rec = fits ? lrec[j] : recs[beg + j];
        const int r = (int)(rec >> 32) - rb;
        const int rank = atomicAdd(&cnt[r], 1);
        pairs[beg + off[r] + rank] = (unsigned int)(rec & 0xFFFFFFFFu);
    }
}

// ---------------------------------------------------------------------------
// Kernel 6: CSR-vector SpMM, fused finalize. One wave per src row; 32 lanes
// per edge (ushort2 = 2 features/lane), 2 edges in flight per half,
// unrolled x8 (16 edges/iteration).
// ---------------------------------------------------------------------------
__global__ __launch_bounds__(256) void spmm_kernel(
    const int* __restrict__ rowptr,
    const unsigned int* __restrict__ pairs,
    const unsigned short* __restrict__ h,   // bf16 [NN, FOUT]
    const int* __restrict__ flags,
    void* __restrict__ out)
{
    const int wave = threadIdx.x >> 6;
    const int lane = threadIdx.x & 63;
    const int half = lane >> 5;
    const int sl   = lane & 31;
    const int row  = blockIdx.x * 4 + wave;

    const int beg = rowptr[row];
    const int end = rowptr[row + 1];

    float acc0 = 0.f, acc1 = 0.f, rsum = 0.f;
    int j = beg;
    for (; j + 15 < end; j += 16) {
        unsigned int u[8];
        ushort2 hv[8];
        #pragma unroll
        for (int k = 0; k < 8; ++k) u[k] = pairs[j + 2 * k + half];
        #pragma unroll
        for (int k = 0; k < 8; ++k)
            hv[k] = *(const ushort2*)&h[(long)(u[k] >> 16) * FOUT + 2 * sl];
        #pragma unroll
        for (int k = 0; k < 8; ++k) {
            const float v = bf16_to_f32((unsigned short)u[k]);
            rsum += v;
            acc0 = fmaf(v, bf16_to_f32(hv[k].x), acc0);
            acc1 = fmaf(v, bf16_to_f32(hv[k].y), acc1);
        }
    }
    for (; j + 1 < end; j += 2) {
        const unsigned int u = pairs[j + half];
        const ushort2 hv = *(const ushort2*)&h[(long)(u >> 16) * FOUT + 2 * sl];
        const float v = bf16_to_f32((unsigned short)u);
        rsum += v;
        acc0 = fmaf(v, bf16_to_f32(hv.x), acc0);
        acc1 = fmaf(v, bf16_to_f32(hv.y), acc1);
    }
    if (j < end && half == 0) {
        const unsigned int u = pairs[j];
        const ushort2 hv = *(const ushort2*)&h[(long)(u >> 16) * FOUT + 2 * sl];
        const float v = bf16_to_f32((unsigned short)u);
        rsum += v;
        acc0 = fmaf(v, bf16_to_f32(hv.x), acc0);
        acc1 = fmaf(v, bf16_to_f32(hv.y), acc1);
    }

    acc0 += __shfl_xor(acc0, 32, 64);
    acc1 += __shfl_xor(acc1, 32, 64);
    rsum += __shfl_xor(rsum, 32, 64);

    if (half == 0) {
        const float inv = 1.f / rsum;
        float q0 = acc0 * inv;
        float q1 = acc1 * inv;
        q0 = q0 > 0.f ? q0 : (__expf(q0) - 1.f);
        q1 = q1 > 0.f ? q1 : (__expf(q1) - 1.f);
        if (flags[0]) {
            float2* o = (float2*)((float*)out + (long)row * FOUT + 2 * sl);
            *o = make_float2(q0, q1);
        } else {
            ushort2* o = (ushort2*)((unsigned short*)out + (long)row * FOUT + 2 * sl);
            *o = make_ushort2(f32_to_bf16_rne(q0), f32_to_bf16_rne(q1));
        }
    }
}

extern "C" void kernel_launch(void* const* d_in, const int* in_sizes, int n_in,
                              void* d_out, int out_size, void* d_ws, size_t ws_size,
                              hipStream_t stream) {
    const void* inp  = d_in[0];
    const void* Mv   = d_in[1];
    const void* W    = d_in[2];
    const void* a    = d_in[3];
    const int*  edge = (const int*)d_in[4];

    // ws: flags | h bf16[NN*64] | s1[NN] | s2[NN] | rowptr[NN+1] | bcnt[NB] |
    //     base[NB+1] | bcur[NB] | pairs u32[EE] | recs u64[EE]
    char* p = (char*)d_ws;
    int*                flags  = (int*)p;            p += 256;
    unsigned short*     h      = (unsigned short*)p; p += ((size_t)NN * FOUT * 2 + 255) / 256 * 256;
    float*              s1     = (float*)p;          p += ((size_t)NN * 4 + 255) / 256 * 256;
    float*              s2     = (float*)p;          p += ((size_t)NN * 4 + 255) / 256 * 256;
    int*                rowptr = (int*)p;            p += ((size_t)(NN + 1) * 4 + 255) / 256 * 256;
    int*                bcnt   = (int*)p;            p += ((size_t)NB * 4 + 255) / 256 * 256;
    int*                base   = (int*)p;            p += ((size_t)(NB + 1) * 4 + 255) / 256 * 256;
    int*                bcur   = (int*)p;            p += ((size_t)NB * 4 + 255) / 256 * 256;
    unsigned int*       pairs  = (unsigned int*)p;   p += ((size_t)EE * 4 + 255) / 256 * 256;
    unsigned long long* recs   = (unsigned long long*)p;

    detect_kernel<<<4, 256, 0, stream>>>(inp, Mv, W, a, flags);
    hipMemsetAsync(bcnt, 0, (size_t)NB * sizeof(int), stream);
    mfma_gemm_kernel<<<NN / 16, 256, 0, stream>>>(inp, W, a, flags, h, s1, s2);
    bucket_hist_kernel<<<HGRID, 256, 0, stream>>>(edge, bcnt);
    bucket_scan_kernel<<<1, 1024, 0, stream>>>(bcnt, base, bcur);
    partition_kernel<<<PGRID, 256, 0, stream>>>(edge, Mv, flags, s1, s2, bcur, recs);
    bucket_csr_kernel<<<NB, 256, 0, stream>>>(base, recs, pairs, rowptr);
    spmm_kernel<<<NN / 4, 256, 0, stream>>>(rowptr, pairs, h, flags, d_out);
}

// Round 10
// 234.770 us; speedup vs baseline: 1.1484x; 1.1484x over previous
//
#include <hip/hip_runtime.h>
#include <hip/hip_bf16.h>

#define NN   50000
#define EE   1600000
#define FIN  128
#define FOUT 64
#define BETA  0.5f
#define ALPHA 0.2f
#define SBW    256          // src rows per super-bucket
#define NB2    196          // ceil(NN/SBW)
#define RCAP   9000         // fixed region capacity (mean 8163 + ~9 sigma)
#define PGRID  400          // partition blocks
#define PCHUNK 4000         // EE/PGRID exact; avg run/bucket = 20 recs = 163 B
#define CAP2   8192         // csr LDS record cache (64 KB); per-rec global fallback
#define XS     152          // gemm LDS stride (bf16 elems)

typedef __attribute__((ext_vector_type(8))) short short8;
typedef __attribute__((ext_vector_type(4))) float float4v;

__device__ __forceinline__ float load_any(const void* p, long i, int isf32) {
    if (isf32) return ((const float*)p)[i];
    unsigned int b = ((unsigned int)(((const unsigned short*)p)[i])) << 16;
    return __uint_as_float(b);
}

__device__ __forceinline__ unsigned short f32_to_bf16_rne(float f) {
    unsigned int b = __float_as_uint(f);
    return (unsigned short)((b + 0x7FFF + ((b >> 16) & 1)) >> 16);
}

__device__ __forceinline__ float bf16_to_f32(unsigned short u) {
    return __uint_as_float(((unsigned int)u) << 16);
}

// ---------------------------------------------------------------------------
// Kernel 0: sampled dtype detection. flags[t]=1 means fp32.
// ---------------------------------------------------------------------------
__global__ __launch_bounds__(256) void detect_kernel(
    const void* inp, const void* Mv, const void* W, const void* a, int* flags)
{
    const void* ptrs[4] = { inp, Mv, W, a };
    const long  cnts[4] = { (long)NN * FIN, (long)EE, (long)FIN * FOUT, 2L * FOUT };
    const int t = blockIdx.x;
    const unsigned short* p = (const unsigned short*)ptrs[t];
    const long half = cnts[t] >> 1;
    long step = half / 256; if (step == 0) step = 1;
    const long pos = 2 * (((long)threadIdx.x * step) % half);

    const float v = bf16_to_f32(p[pos]);
    const int bad = (isnan(v) || fabsf(v) > 1e4f) ? 1 : 0;

    __shared__ int sbad[256];
    sbad[threadIdx.x] = bad;
    __syncthreads();
    for (int s = 128; s > 0; s >>= 1) {
        if (threadIdx.x < (unsigned)s) sbad[threadIdx.x] |= sbad[threadIdx.x + s];
        __syncthreads();
    }
    if (threadIdx.x == 0) flags[t] = sbad[0];
}

// ---------------------------------------------------------------------------
// Kernel 1: MFMA gemm (R9-validated). 16 rows/block; 4x mfma_f32_16x16x32_bf16
// per wave over K=128; fused s1/s2.
// ---------------------------------------------------------------------------
__global__ __launch_bounds__(256) void mfma_gemm_kernel(
    const void* __restrict__ inp,
    const void* __restrict__ W,
    const void* __restrict__ a,
    const int* __restrict__ flags,
    unsigned short* __restrict__ h,
    float* __restrict__ s1,
    float* __restrict__ s2)
{
    __shared__ unsigned short Xs[16 * XS];
    __shared__ unsigned short Wt[64 * XS];
    __shared__ float part1[4][16];
    __shared__ float part2[4][16];

    const int tid  = threadIdx.x;
    const int wave = tid >> 6;
    const int lane = tid & 63;
    const int quad = lane >> 4;
    const int col  = lane & 15;
    const int rb   = blockIdx.x * 16;

    const int fI = flags[0], fW = flags[2], fA = flags[3];

    for (int i = tid; i < 16 * FIN; i += 256) {
        const int r = i >> 7, k = i & 127;
        Xs[r * XS + k] = f32_to_bf16_rne(load_any(inp, (long)(rb + r) * FIN + k, fI));
    }
    for (int i = tid; i < FIN * FOUT; i += 256) {
        const int k = i & 127, n = i >> 7;
        Wt[n * XS + k] = f32_to_bf16_rne(load_any(W, (long)k * FOUT + n, fW));
    }
    __syncthreads();

    const int nb = wave * 16;
    float4v acc = { 0.f, 0.f, 0.f, 0.f };
    #pragma unroll
    for (int k0 = 0; k0 < FIN; k0 += 32) {
        const short8 af = *(const short8*)&Xs[col * XS + k0 + quad * 8];
        const short8 bf = *(const short8*)&Wt[(nb + col) * XS + k0 + quad * 8];
        acc = __builtin_amdgcn_mfma_f32_16x16x32_bf16(af, bf, acc, 0, 0, 0);
    }

    #pragma unroll
    for (int r = 0; r < 4; ++r)
        h[(long)(rb + quad * 4 + r) * FOUT + nb + col] = f32_to_bf16_rne(acc[r]);

    const float a1 = load_any(a, nb + col, fA);
    const float a2 = load_any(a, 64 + nb + col, fA);
    #pragma unroll
    for (int r = 0; r < 4; ++r) {
        float v1 = acc[r] * a1;
        float v2 = acc[r] * a2;
        #pragma unroll
        for (int o = 1; o < 16; o <<= 1) {
            v1 += __shfl_xor(v1, o, 64);
            v2 += __shfl_xor(v2, o, 64);
        }
        if (col == 0) {
            part1[wave][quad * 4 + r] = v1;
            part2[wave][quad * 4 + r] = v2;
        }
    }
    __syncthreads();
    if (tid < 16) {
        s1[rb + tid] = part1[0][tid] + part1[1][tid] + part1[2][tid] + part1[3][tid];
        s2[rb + tid] = part2[0][tid] + part2[1][tid] + part2[2][tid] + part2[3][tid];
    }
}

// ---------------------------------------------------------------------------
// Kernel 2: partition into 196 super-buckets with FIXED regions (b*RCAP).
// Per block: LDS-count chunk, reserve one contiguous run per bucket (single
// global atomic), append u64 recs. Runs avg 20 recs = 163 B, written within
// the block's pass-B window -> low write-allocate amplification.
// Record: src<<32 | dst<<16 | bf16(edge_e).
// ---------------------------------------------------------------------------
__global__ __launch_bounds__(256) void partition_kernel(
    const int* __restrict__ edge,
    const void* __restrict__ Mv,
    const int* __restrict__ flags,
    const float* __restrict__ s1,
    const float* __restrict__ s2,
    int* __restrict__ bcur,              // [NB2], zeroed; per-bucket count
    unsigned long long* __restrict__ recs)
{
    __shared__ int lcnt[NB2];
    __shared__ int lbase[NB2];
    const int tid = threadIdx.x;
    const int fM = flags[1];
    const int e0 = blockIdx.x * PCHUNK;

    if (tid < NB2) lcnt[tid] = 0;
    __syncthreads();

    for (int e = e0 + tid; e < e0 + PCHUNK; e += 256)
        atomicAdd(&lcnt[edge[e] >> 8], 1);
    __syncthreads();

    if (tid < NB2) {
        const int c = lcnt[tid];
        const int o = c ? atomicAdd(&bcur[tid], c) : 0;
        lbase[tid] = tid * RCAP + o;
        lcnt[tid] = 0;                 // reuse as rank counter
    }
    __syncthreads();

    for (int e = e0 + tid; e < e0 + PCHUNK; e += 256) {
        const int src = edge[e];
        const int dst = edge[EE + e];
        const float bias = load_any(Mv, e, fM) * BETA + (1.f - BETA);
        const float x  = s1[src] + bias * s2[dst];
        const float lr = x > 0.f ? x : ALPHA * x;
        const float ee = __expf(lr);
        const int b = src >> 8;
        const int r = atomicAdd(&lcnt[b], 1);
        const int pos = lbase[b] + r;
        if (pos < (b + 1) * RCAP)      // graceful guard (P ~ 1e-17)
            recs[pos] = ((unsigned long long)(unsigned)src << 32)
                      | ((unsigned long long)(unsigned)dst << 16)
                      | (unsigned long long)f32_to_bf16_rne(ee);
    }
}

// ---------------------------------------------------------------------------
// Kernel 3: per-super-bucket CSR finalize + row ranges. One block per bucket:
// stream its region (LDS cache first CAP2 recs, global fallback beyond),
// count 256 rows, 4-wave scan -> rowbeg/rowend, rank-and-write 4 B pairs into
// the bucket's contiguous region slice (L2-resident, ~32 KB).
// ---------------------------------------------------------------------------
__global__ __launch_bounds__(256) void bucket_csr_kernel(
    const int* __restrict__ bcur,
    const unsigned long long* __restrict__ recs,
    unsigned int* __restrict__ pairs,
    int* __restrict__ rowbeg,
    int* __restrict__ rowend)
{
    __shared__ unsigned long long lrec[CAP2];   // 64 KB
    __shared__ int cnt[SBW];
    __shared__ int off[SBW];
    __shared__ int wsum[4];
    const int b    = blockIdx.x;
    const int tid  = threadIdx.x;
    const int wave = tid >> 6;
    const int lane = tid & 63;
    const int rb   = b * SBW;
    const int beg  = b * RCAP;

    int n = bcur[b]; if (n > RCAP) n = RCAP;

    cnt[tid] = 0;
    __syncthreads();

    for (int j = tid; j < n; j += 256) {
        const unsigned long long rec = recs[beg + j];
        if (j < CAP2) lrec[j] = rec;
        atomicAdd(&cnt[(int)(rec >> 32) - rb], 1);
    }
    __syncthreads();

    // exclusive scan of 256 row counts (4-wave)
    const int c = cnt[tid];
    int x = c;
    #pragma unroll
    for (int o = 1; o < 64; o <<= 1) {
        int y = __shfl_up(x, o, 64);
        if (lane >= o) x += y;
    }
    if (lane == 63) wsum[wave] = x;
    __syncthreads();
    int wb = 0;
    for (int w = 0; w < wave; ++w) wb += wsum[w];
    const int myoff = wb + x - c;
    off[tid] = myoff;
    const int row = rb + tid;
    if (row < NN) {
        rowbeg[row] = beg + myoff;
        rowend[row] = beg + myoff + c;
    }
    cnt[tid] = 0;
    __syncthreads();

    for (int j = tid; j < n; j += 256) {
        const unsigned long long rec = (j < CAP2) ? lrec[j] : recs[beg + j];
        const int r = (int)(rec >> 32) - rb;
        const int rank = atomicAdd(&cnt[r], 1);
        pairs[beg + off[r] + rank] = (unsigned int)(rec & 0xFFFFFFFFu);
    }
}

// ---------------------------------------------------------------------------
// Kernel 4: CSR-vector SpMM, fused finalize. One wave per src row; 32 lanes
// per edge (ushort2), 2 edges in flight per half, unrolled x8.
// ---------------------------------------------------------------------------
__global__ __launch_bounds__(256) void spmm_kernel(
    const int* __restrict__ rowbeg,
    const int* __restrict__ rowend,
    const unsigned int* __restrict__ pairs,
    const unsigned short* __restrict__ h,   // bf16 [NN, FOUT]
    const int* __restrict__ flags,
    void* __restrict__ out)
{
    const int wave = threadIdx.x >> 6;
    const int lane = threadIdx.x & 63;
    const int half = lane >> 5;
    const int sl   = lane & 31;
    const int row  = blockIdx.x * 4 + wave;

    const int beg = rowbeg[row];
    const int end = rowend[row];

    float acc0 = 0.f, acc1 = 0.f, rsum = 0.f;
    int j = beg;
    for (; j + 15 < end; j += 16) {
        unsigned int u[8];
        ushort2 hv[8];
        #pragma unroll
        for (int k = 0; k < 8; ++k) u[k] = pairs[j + 2 * k + half];
        #pragma unroll
        for (int k = 0; k < 8; ++k)
            hv[k] = *(const ushort2*)&h[(long)(u[k] >> 16) * FOUT + 2 * sl];
        #pragma unroll
        for (int k = 0; k < 8; ++k) {
            const float v = bf16_to_f32((unsigned short)u[k]);
            rsum += v;
            acc0 = fmaf(v, bf16_to_f32(hv[k].x), acc0);
            acc1 = fmaf(v, bf16_to_f32(hv[k].y), acc1);
        }
    }
    for (; j + 1 < end; j += 2) {
        const unsigned int u = pairs[j + half];
        const ushort2 hv = *(const ushort2*)&h[(long)(u >> 16) * FOUT + 2 * sl];
        const float v = bf16_to_f32((unsigned short)u);
        rsum += v;
        acc0 = fmaf(v, bf16_to_f32(hv.x), acc0);
        acc1 = fmaf(v, bf16_to_f32(hv.y), acc1);
    }
    if (j < end && half == 0) {
        const unsigned int u = pairs[j];
        const ushort2 hv = *(const ushort2*)&h[(long)(u >> 16) * FOUT + 2 * sl];
        const float v = bf16_to_f32((unsigned short)u);
        rsum += v;
        acc0 = fmaf(v, bf16_to_f32(hv.x), acc0);
        acc1 = fmaf(v, bf16_to_f32(hv.y), acc1);
    }

    acc0 += __shfl_xor(acc0, 32, 64);
    acc1 += __shfl_xor(acc1, 32, 64);
    rsum += __shfl_xor(rsum, 32, 64);

    if (half == 0) {
        const float inv = 1.f / rsum;
        float q0 = acc0 * inv;
        float q1 = acc1 * inv;
        q0 = q0 > 0.f ? q0 : (__expf(q0) - 1.f);
        q1 = q1 > 0.f ? q1 : (__expf(q1) - 1.f);
        if (flags[0]) {
            float2* o = (float2*)((float*)out + (long)row * FOUT + 2 * sl);
            *o = make_float2(q0, q1);
        } else {
            ushort2* o = (ushort2*)((unsigned short*)out + (long)row * FOUT + 2 * sl);
            *o = make_ushort2(f32_to_bf16_rne(q0), f32_to_bf16_rne(q1));
        }
    }
}

extern "C" void kernel_launch(void* const* d_in, const int* in_sizes, int n_in,
                              void* d_out, int out_size, void* d_ws, size_t ws_size,
                              hipStream_t stream) {
    const void* inp  = d_in[0];
    const void* Mv   = d_in[1];
    const void* W    = d_in[2];
    const void* a    = d_in[3];
    const int*  edge = (const int*)d_in[4];

    // ws: flags | h bf16[NN*64] | s1[NN] | s2[NN] | rowbeg[NN] | rowend[NN] |
    //     bcur[NB2] | pairs u32[NB2*RCAP] | recs u64[NB2*RCAP]
    char* p = (char*)d_ws;
    int*                flags  = (int*)p;            p += 256;
    unsigned short*     h      = (unsigned short*)p; p += ((size_t)NN * FOUT * 2 + 255) / 256 * 256;
    float*              s1     = (float*)p;          p += ((size_t)NN * 4 + 255) / 256 * 256;
    float*              s2     = (float*)p;          p += ((size_t)NN * 4 + 255) / 256 * 256;
    int*                rowbeg = (int*)p;            p += ((size_t)NN * 4 + 255) / 256 * 256;
    int*                rowend = (int*)p;            p += ((size_t)NN * 4 + 255) / 256 * 256;
    int*                bcur   = (int*)p;            p += ((size_t)NB2 * 4 + 255) / 256 * 256;
    unsigned int*       pairs  = (unsigned int*)p;   p += ((size_t)NB2 * RCAP * 4 + 255) / 256 * 256;
    unsigned long long* recs   = (unsigned long long*)p;

    detect_kernel<<<4, 256, 0, stream>>>(inp, Mv, W, a, flags);
    hipMemsetAsync(bcur, 0, (size_t)NB2 * sizeof(int), stream);
    mfma_gemm_kernel<<<NN / 16, 256, 0, stream>>>(inp, W, a, flags, h, s1, s2);
    partition_kernel<<<PGRID, 256, 0, stream>>>(edge, Mv, flags, s1, s2, bcur, recs);
    bucket_csr_kernel<<<NB2, 256, 0, stream>>>(bcur, recs, pairs, rowbeg, rowend);
    spmm_kernel<<<NN / 4, 256, 0, stream>>>(rowbeg, rowend, pairs, h, flags, d_out);
}

// Round 11
// 192.816 us; speedup vs baseline: 1.3983x; 1.2176x over previous
//
#include <hip/hip_runtime.h>
#include <hip/hip_bf16.h>

#define NN   50000
#define EE   1600000
#define FIN  128
#define FOUT 64
#define BETA  0.5f
#define ALPHA 0.2f
#define SBW    256          // src rows per super-bucket
#define NB2    196          // ceil(NN/SBW)
#define RCAP   9000         // fixed region capacity (mean 8163 + ~9 sigma)
#define PGRID  400          // partition blocks
#define PCHUNK 4000         // EE/PGRID exact
#define CAP2   8192         // csr LDS record cache (64 KB)
#define XS     136          // gemm X LDS stride (bf16 elems, 16B-aligned rows)

typedef __attribute__((ext_vector_type(8))) short short8;
typedef __attribute__((ext_vector_type(8))) unsigned short ushort8v;
typedef __attribute__((ext_vector_type(4))) float float4v;

__device__ __forceinline__ float load_any(const void* p, long i, int isf32) {
    if (isf32) return ((const float*)p)[i];
    unsigned int b = ((unsigned int)(((const unsigned short*)p)[i])) << 16;
    return __uint_as_float(b);
}

__device__ __forceinline__ unsigned short f32_to_bf16_rne(float f) {
    unsigned int b = __float_as_uint(f);
    return (unsigned short)((b + 0x7FFF + ((b >> 16) & 1)) >> 16);
}

__device__ __forceinline__ float bf16_to_f32(unsigned short u) {
    return __uint_as_float(((unsigned int)u) << 16);
}

// ---------------------------------------------------------------------------
// Kernel 0: sampled dtype detection. flags[t]=1 means fp32.
// ---------------------------------------------------------------------------
__global__ __launch_bounds__(256) void detect_kernel(
    const void* inp, const void* Mv, const void* W, const void* a, int* flags)
{
    const void* ptrs[4] = { inp, Mv, W, a };
    const long  cnts[4] = { (long)NN * FIN, (long)EE, (long)FIN * FOUT, 2L * FOUT };
    const int t = blockIdx.x;
    const unsigned short* p = (const unsigned short*)ptrs[t];
    const long half = cnts[t] >> 1;
    long step = half / 256; if (step == 0) step = 1;
    const long pos = 2 * (((long)threadIdx.x * step) % half);

    const float v = bf16_to_f32(p[pos]);
    const int bad = (isnan(v) || fabsf(v) > 1e4f) ? 1 : 0;

    __shared__ int sbad[256];
    sbad[threadIdx.x] = bad;
    __syncthreads();
    for (int s = 128; s > 0; s >>= 1) {
        if (threadIdx.x < (unsigned)s) sbad[threadIdx.x] |= sbad[threadIdx.x + s];
        __syncthreads();
    }
    if (threadIdx.x == 0) flags[t] = sbad[0];
}

// ---------------------------------------------------------------------------
// Kernel 0b: one-time W transpose -> Wt[n][k] bf16 (16 KB). Hoists the
// uncoalesced transpose out of the 3125-block gemm (R10's 68 us was 25.6M
// line-granular W reads -- staging-bound, not MFMA-bound).
// ---------------------------------------------------------------------------
__global__ __launch_bounds__(256) void wt_kernel(
    const void* __restrict__ W, const int* __restrict__ flags,
    unsigned short* __restrict__ Wt)
{
    const int fW = flags[2];
    const int i = blockIdx.x * 256 + threadIdx.x;
    if (i < FIN * FOUT) {
        const int k = i >> 6, n = i & 63;           // read W coalesced
        Wt[n * FIN + k] = f32_to_bf16_rne(load_any(W, i, fW));
    }
}

// ---------------------------------------------------------------------------
// Kernel 1: MFMA gemm. 16 rows/block (3125 blocks exact). X staged to LDS
// with ONE 16 B vector load/thread (dtype-branched); B-fragments read
// directly from global Wt (L1-hot 16 KB). 4x mfma_f32_16x16x32_bf16 per
// wave over K=128. Fused s1/s2 projections.
// C layout: col=lane&15, row=quad*4+reg. A: A[m=lane&15][k=quad*8+j].
// ---------------------------------------------------------------------------
__global__ __launch_bounds__(256) void mfma_gemm_kernel(
    const void* __restrict__ inp,
    const unsigned short* __restrict__ Wt,   // bf16 [64][128]
    const void* __restrict__ a,
    const int* __restrict__ flags,
    unsigned short* __restrict__ h,
    float* __restrict__ s1,
    float* __restrict__ s2)
{
    __shared__ unsigned short Xs[16 * XS];   // 4.25 KB
    __shared__ float part1[4][16];
    __shared__ float part2[4][16];

    const int tid  = threadIdx.x;
    const int wave = tid >> 6;
    const int lane = tid & 63;
    const int quad = lane >> 4;
    const int col  = lane & 15;
    const int rb   = blockIdx.x * 16;

    const int fI = flags[0], fA = flags[3];

    // stage X: one 16 B vector load per thread (16 rows x 128 k exactly)
    {
        const int r = tid >> 4, k8 = (tid & 15) * 8;
        if (!fI) {
            const unsigned short* src = (const unsigned short*)inp + (long)(rb + r) * FIN + k8;
            *(ushort8v*)&Xs[r * XS + k8] = *(const ushort8v*)src;
        } else {
            const float* src = (const float*)inp + (long)(rb + r) * FIN + k8;
            ushort8v v;
            #pragma unroll
            for (int j = 0; j < 8; ++j) v[j] = f32_to_bf16_rne(src[j]);
            *(ushort8v*)&Xs[r * XS + k8] = v;
        }
    }
    __syncthreads();

    const int nb = wave * 16;
    float4v acc = { 0.f, 0.f, 0.f, 0.f };
    #pragma unroll
    for (int k0 = 0; k0 < FIN; k0 += 32) {
        const short8 af = *(const short8*)&Xs[col * XS + k0 + quad * 8];
        const short8 bf = *(const short8*)&Wt[(long)(nb + col) * FIN + k0 + quad * 8];
        acc = __builtin_amdgcn_mfma_f32_16x16x32_bf16(af, bf, acc, 0, 0, 0);
    }

    #pragma unroll
    for (int r = 0; r < 4; ++r)
        h[(long)(rb + quad * 4 + r) * FOUT + nb + col] = f32_to_bf16_rne(acc[r]);

    const float a1 = load_any(a, nb + col, fA);
    const float a2 = load_any(a, 64 + nb + col, fA);
    #pragma unroll
    for (int r = 0; r < 4; ++r) {
        float v1 = acc[r] * a1;
        float v2 = acc[r] * a2;
        #pragma unroll
        for (int o = 1; o < 16; o <<= 1) {
            v1 += __shfl_xor(v1, o, 64);
            v2 += __shfl_xor(v2, o, 64);
        }
        if (col == 0) {
            part1[wave][quad * 4 + r] = v1;
            part2[wave][quad * 4 + r] = v2;
        }
    }
    __syncthreads();
    if (tid < 16) {
        s1[rb + tid] = part1[0][tid] + part1[1][tid] + part1[2][tid] + part1[3][tid];
        s2[rb + tid] = part2[0][tid] + part2[1][tid] + part2[2][tid] + part2[3][tid];
    }
}

// ---------------------------------------------------------------------------
// Kernel 2: partition into 196 super-buckets with FIXED regions (b*RCAP).
// Per block: LDS-count chunk, reserve one contiguous run per bucket (single
// global atomic), append u64 recs. Record: src<<32 | dst<<16 | bf16(edge_e).
// ---------------------------------------------------------------------------
__global__ __launch_bounds__(256) void partition_kernel(
    const int* __restrict__ edge,
    const void* __restrict__ Mv,
    const int* __restrict__ flags,
    const float* __restrict__ s1,
    const float* __restrict__ s2,
    int* __restrict__ bcur,              // [NB2], zeroed; per-bucket count
    unsigned long long* __restrict__ recs)
{
    __shared__ int lcnt[NB2];
    __shared__ int lbase[NB2];
    const int tid = threadIdx.x;
    const int fM = flags[1];
    const int e0 = blockIdx.x * PCHUNK;

    if (tid < NB2) lcnt[tid] = 0;
    __syncthreads();

    for (int e = e0 + tid; e < e0 + PCHUNK; e += 256)
        atomicAdd(&lcnt[edge[e] >> 8], 1);
    __syncthreads();

    if (tid < NB2) {
        const int c = lcnt[tid];
        const int o = c ? atomicAdd(&bcur[tid], c) : 0;
        lbase[tid] = tid * RCAP + o;
        lcnt[tid] = 0;                 // reuse as rank counter
    }
    __syncthreads();

    for (int e = e0 + tid; e < e0 + PCHUNK; e += 256) {
        const int src = edge[e];
        const int dst = edge[EE + e];
        const float bias = load_any(Mv, e, fM) * BETA + (1.f - BETA);
        const float x  = s1[src] + bias * s2[dst];
        const float lr = x > 0.f ? x : ALPHA * x;
        const float ee = __expf(lr);
        const int b = src >> 8;
        const int r = atomicAdd(&lcnt[b], 1);
        const int pos = lbase[b] + r;
        if (pos < (b + 1) * RCAP)      // graceful guard (P ~ 1e-17)
            recs[pos] = ((unsigned long long)(unsigned)src << 32)
                      | ((unsigned long long)(unsigned)dst << 16)
                      | (unsigned long long)f32_to_bf16_rne(ee);
    }
}

// ---------------------------------------------------------------------------
// Kernel 3: per-super-bucket CSR finalize + row ranges.
// ---------------------------------------------------------------------------
__global__ __launch_bounds__(256) void bucket_csr_kernel(
    const int* __restrict__ bcur,
    const unsigned long long* __restrict__ recs,
    unsigned int* __restrict__ pairs,
    int* __restrict__ rowbeg,
    int* __restrict__ rowend)
{
    __shared__ unsigned long long lrec[CAP2];   // 64 KB
    __shared__ int cnt[SBW];
    __shared__ int off[SBW];
    __shared__ int wsum[4];
    const int b    = blockIdx.x;
    const int tid  = threadIdx.x;
    const int wave = tid >> 6;
    const int lane = tid & 63;
    const int rb   = b * SBW;
    const int beg  = b * RCAP;

    int n = bcur[b]; if (n > RCAP) n = RCAP;

    cnt[tid] = 0;
    __syncthreads();

    for (int j = tid; j < n; j += 256) {
        const unsigned long long rec = recs[beg + j];
        if (j < CAP2) lrec[j] = rec;
        atomicAdd(&cnt[(int)(rec >> 32) - rb], 1);
    }
    __syncthreads();

    const int c = cnt[tid];
    int x = c;
    #pragma unroll
    for (int o = 1; o < 64; o <<= 1) {
        int y = __shfl_up(x, o, 64);
        if (lane >= o) x += y;
    }
    if (lane == 63) wsum[wave] = x;
    __syncthreads();
    int wb = 0;
    for (int w = 0; w < wave; ++w) wb += wsum[w];
    const int myoff = wb + x - c;
    off[tid] = myoff;
    const int row = rb + tid;
    if (row < NN) {
        rowbeg[row] = beg + myoff;
        rowend[row] = beg + myoff + c;
    }
    cnt[tid] = 0;
    __syncthreads();

    for (int j = tid; j < n; j += 256) {
        const unsigned long long rec = (j < CAP2) ? lrec[j] : recs[beg + j];
        const int r = (int)(rec >> 32) - rb;
        const int rank = atomicAdd(&cnt[r], 1);
        pairs[beg + off[r] + rank] = (unsigned int)(rec & 0xFFFFFFFFu);
    }
}

// ---------------------------------------------------------------------------
// Kernel 4: CSR-vector SpMM, fused finalize. One wave per src row; 32 lanes
// per edge (ushort2), 2 edges in flight per half, unrolled x8.
// ---------------------------------------------------------------------------
__global__ __launch_bounds__(256) void spmm_kernel(
    const int* __restrict__ rowbeg,
    const int* __restrict__ rowend,
    const unsigned int* __restrict__ pairs,
    const unsigned short* __restrict__ h,   // bf16 [NN, FOUT]
    const int* __restrict__ flags,
    void* __restrict__ out)
{
    const int wave = threadIdx.x >> 6;
    const int lane = threadIdx.x & 63;
    const int half = lane >> 5;
    const int sl   = lane & 31;
    const int row  = blockIdx.x * 4 + wave;

    const int beg = rowbeg[row];
    const int end = rowend[row];

    float acc0 = 0.f, acc1 = 0.f, rsum = 0.f;
    int j = beg;
    for (; j + 15 < end; j += 16) {
        unsigned int u[8];
        ushort2 hv[8];
        #pragma unroll
        for (int k = 0; k < 8; ++k) u[k] = pairs[j + 2 * k + half];
        #pragma unroll
        for (int k = 0; k < 8; ++k)
            hv[k] = *(const ushort2*)&h[(long)(u[k] >> 16) * FOUT + 2 * sl];
        #pragma unroll
        for (int k = 0; k < 8; ++k) {
            const float v = bf16_to_f32((unsigned short)u[k]);
            rsum += v;
            acc0 = fmaf(v, bf16_to_f32(hv[k].x), acc0);
            acc1 = fmaf(v, bf16_to_f32(hv[k].y), acc1);
        }
    }
    for (; j + 1 < end; j += 2) {
        const unsigned int u = pairs[j + half];
        const ushort2 hv = *(const ushort2*)&h[(long)(u >> 16) * FOUT + 2 * sl];
        const float v = bf16_to_f32((unsigned short)u);
        rsum += v;
        acc0 = fmaf(v, bf16_to_f32(hv.x), acc0);
        acc1 = fmaf(v, bf16_to_f32(hv.y), acc1);
    }
    if (j < end && half == 0) {
        const unsigned int u = pairs[j];
        const ushort2 hv = *(const ushort2*)&h[(long)(u >> 16) * FOUT + 2 * sl];
        const float v = bf16_to_f32((unsigned short)u);
        rsum += v;
        acc0 = fmaf(v, bf16_to_f32(hv.x), acc0);
        acc1 = fmaf(v, bf16_to_f32(hv.y), acc1);
    }

    acc0 += __shfl_xor(acc0, 32, 64);
    acc1 += __shfl_xor(acc1, 32, 64);
    rsum += __shfl_xor(rsum, 32, 64);

    if (half == 0) {
        const float inv = 1.f / rsum;
        float q0 = acc0 * inv;
        float q1 = acc1 * inv;
        q0 = q0 > 0.f ? q0 : (__expf(q0) - 1.f);
        q1 = q1 > 0.f ? q1 : (__expf(q1) - 1.f);
        if (flags[0]) {
            float2* o = (float2*)((float*)out + (long)row * FOUT + 2 * sl);
            *o = make_float2(q0, q1);
        } else {
            ushort2* o = (ushort2*)((unsigned short*)out + (long)row * FOUT + 2 * sl);
            *o = make_ushort2(f32_to_bf16_rne(q0), f32_to_bf16_rne(q1));
        }
    }
}

extern "C" void kernel_launch(void* const* d_in, const int* in_sizes, int n_in,
                              void* d_out, int out_size, void* d_ws, size_t ws_size,
                              hipStream_t stream) {
    const void* inp  = d_in[0];
    const void* Mv   = d_in[1];
    const void* W    = d_in[2];
    const void* a    = d_in[3];
    const int*  edge = (const int*)d_in[4];

    // ws: flags | Wt bf16[64*128] | h bf16[NN*64] | s1[NN] | s2[NN] |
    //     rowbeg[NN] | rowend[NN] | bcur[NB2] | pairs u32[NB2*RCAP] | recs u64[NB2*RCAP]
    char* p = (char*)d_ws;
    int*                flags  = (int*)p;            p += 256;
    unsigned short*     Wt     = (unsigned short*)p; p += ((size_t)FOUT * FIN * 2 + 255) / 256 * 256;
    unsigned short*     h      = (unsigned short*)p; p += ((size_t)NN * FOUT * 2 + 255) / 256 * 256;
    float*              s1     = (float*)p;          p += ((size_t)NN * 4 + 255) / 256 * 256;
    float*              s2     = (float*)p;          p += ((size_t)NN * 4 + 255) / 256 * 256;
    int*                rowbeg = (int*)p;            p += ((size_t)NN * 4 + 255) / 256 * 256;
    int*                rowend = (int*)p;            p += ((size_t)NN * 4 + 255) / 256 * 256;
    int*                bcur   = (int*)p;            p += ((size_t)NB2 * 4 + 255) / 256 * 256;
    unsigned int*       pairs  = (unsigned int*)p;   p += ((size_t)NB2 * RCAP * 4 + 255) / 256 * 256;
    unsigned long long* recs   = (unsigned long long*)p;

    detect_kernel<<<4, 256, 0, stream>>>(inp, Mv, W, a, flags);
    hipMemsetAsync(bcur, 0, (size_t)NB2 * sizeof(int), stream);
    wt_kernel<<<(FIN * FOUT + 255) / 256, 256, 0, stream>>>(W, flags, Wt);
    mfma_gemm_kernel<<<NN / 16, 256, 0, stream>>>(inp, Wt, a, flags, h, s1, s2);
    partition_kernel<<<PGRID, 256, 0, stream>>>(edge, Mv, flags, s1, s2, bcur, recs);
    bucket_csr_kernel<<<NB2, 256, 0, stream>>>(bcur, recs, pairs, rowbeg, rowend);
    spmm_kernel<<<NN / 4, 256, 0, stream>>>(rowbeg, rowend, pairs, h, flags, d_out);
}